// Round 5
// baseline (34.017 us; speedup 1.0000x reference)
//
#include <hip/hip_runtime.h>

#define HH 256
#define WW 256
#define CC 8
#define TY 16
#define LW (WW + 2)          // padded LDS row: col 0 and 257 are zero
#define NSTRIP (HH / TY)     // 16 strips per image

// One block = one TY-row full-width strip of one image. One thread per column.
// Sliding 4-row ring of NORMALIZED affinity channels in LDS; raw next-row
// values prefetched into registers each iteration; rsum carried in registers.
// out(j,x) = cur(j,x) * [ a0(j+1,x+1)+a1(j+1,x)+a2(j+1,x-1)
//                        +a3(j,  x+1)          +a4(j,  x-1)
//                        +a5(j-1,x+1)+a6(j-1,x)+a7(j-1,x-1) ]
//          + coa(j,x) * (1 - rawsum(j,x)),   a_c = aff_c / sum_c|aff_c|
//
// Tuning record (measured):
//   TY=16, 256thr, 4 blk/CU (16 waves/CU): 33.27 us  <- this kernel
//   TY=32, 256thr, 2 blk/CU ( 8 waves/CU): 37.05 us  (occupancy-bound)
//   TY=32, 512thr pair, 2 blk/CU (16 w/CU): 33.73 us (barrier granularity)
// Effective BW here = 201 MB / 33.3 us = 6.05 TB/s = 96% of 6.29 TB/s ceiling.
__global__ __launch_bounds__(256) void cspn_strip(
    const float* __restrict__ aff,   // [B, 8, H, W]
    const float* __restrict__ cur,   // [B, 1, H, W]
    const float* __restrict__ coa,   // [B, 1, H, W]
    float* __restrict__ out)         // [B, 1, H, W]
{
    __shared__ float ring[4][CC][LW];

    // bijective XCD swizzle: 1024 blocks % 8 == 0 -> 128 consecutive per XCD
    // (keeps all 16 strips of an image on one XCD: boundary rows can hit L2)
    const int cpx = gridDim.x >> 3;
    int wg = blockIdx.x;
    wg = (wg & 7) * cpx + (wg >> 3);

    const int b  = wg >> 4;                    // image
    const int y0 = (wg & (NSTRIP - 1)) * TY;   // strip start row
    const int x  = threadIdx.x;                // column 0..255

    // zero the x-pad columns once (4 slots x 8 ch x 2 sides = 64 entries)
    if (threadIdx.x < 64) {
        const int s = threadIdx.x >> 4;
        const int c = (threadIdx.x >> 1) & 7;
        ring[s][c][(threadIdx.x & 1) ? (LW - 1) : 0] = 0.f;
    }

    const size_t plane = (size_t)HH * WW;
    const float* __restrict__ ab = aff + (size_t)b * CC * plane;
    const size_t img = (size_t)b * plane;

    // prime: raw row y0-1 (zeros outside image)
    float r[CC];
    {
        const int yy = y0 - 1;
        const bool inb = ((unsigned)yy < HH);
        #pragma unroll
        for (int c = 0; c < CC; ++c)
            r[c] = inb ? ab[c * plane + (size_t)yy * WW + x] : 0.f;
    }
    float rsum_prev = 0.f;

    __syncthreads();

    for (int y = y0 - 1; y <= y0 + TY; ++y) {
        // ---- prefetch raw row y+1 into registers (hides HBM latency) ----
        float n[CC];
        const int yn = y + 1;
        const bool ldn = (yn <= y0 + TY) && ((unsigned)yn < HH);
        #pragma unroll
        for (int c = 0; c < CC; ++c)
            n[c] = ldn ? ab[c * plane + (size_t)yn * WW + x] : 0.f;

        const int j = y - 1;                 // output row finalized this iter
        const bool emit = (j >= y0);         // j < y0+TY always true here
        float cj = 0.f, oj = 0.f;
        if (emit) {
            cj = cur[img + (size_t)j * WW + x];
            oj = coa[img + (size_t)j * WW + x];
        }

        // ---- normalize row y -> ring slot ----
        float s = 0.f, rs = 0.f;
        #pragma unroll
        for (int c = 0; c < CC; ++c) { s += fabsf(r[c]); rs += r[c]; }
        const float invs = (s > 0.f) ? (1.0f / s) : 0.f;  // 0 for off-image rows
        const int slot = (y + 4) & 3;
        #pragma unroll
        for (int c = 0; c < CC; ++c) ring[slot][c][x + 1] = r[c] * invs;

        __syncthreads();

        // ---- gather output row j (needs rows j-1, j, j+1 in ring) ----
        if (emit) {
            const int sp = (y + 4) & 3;      // row j+1 == y
            const int sc = (y + 3) & 3;      // row j
            const int sm = (y + 2) & 3;      // row j-1
            const int xc = x + 1;
            const float sum =
                ring[sp][0][xc + 1] + ring[sp][1][xc] + ring[sp][2][xc - 1] +
                ring[sc][3][xc + 1]                   + ring[sc][4][xc - 1] +
                ring[sm][5][xc + 1] + ring[sm][6][xc] + ring[sm][7][xc - 1];
            out[img + (size_t)j * WW + x] = cj * sum + oj * (1.0f - rsum_prev);
        }

        rsum_prev = rs;                      // rs of row y -> used when j == y
        #pragma unroll
        for (int c = 0; c < CC; ++c) r[c] = n[c];
    }
}

extern "C" void kernel_launch(void* const* d_in, const int* in_sizes, int n_in,
                              void* d_out, int out_size, void* d_ws, size_t ws_size,
                              hipStream_t stream) {
    const float* aff = (const float*)d_in[0];   // [64, 8, 256, 256]
    const float* cur = (const float*)d_in[1];   // [64, 1, 256, 256]
    const float* coa = (const float*)d_in[2];   // [64, 1, 256, 256]
    float* out = (float*)d_out;                 // [64, 1, 256, 256]

    dim3 grid(64 * NSTRIP);                     // 1024 blocks = 4 per CU, all resident
    dim3 block(256);
    cspn_strip<<<grid, block, 0, stream>>>(aff, cur, coa, out);
}